// Round 2
// baseline (195.608 us; speedup 1.0000x reference)
//
#include <hip/hip_runtime.h>

// ---------------------------------------------------------------------------
// MABClean: setnorm -> {Q,K,V} proj -> 8-head attention -> O proj + residual
//           -> setnorm -> relu -> Wres proj + residual.
// B=4, Nx=Ny=2048, d_model=256, heads=8, head_dim=32. All f32 in/out.
// Compute in f16 MFMA (f32 accum), stats/softmax/residuals in f32.
// ---------------------------------------------------------------------------

typedef _Float16 f16;
typedef _Float16 f16x8 __attribute__((ext_vector_type(8)));
typedef float f32x4 __attribute__((ext_vector_type(4)));

#define DEV static __device__ __forceinline__

DEV void load_lds16(const void* g, void* s) {
  __builtin_amdgcn_global_load_lds(
      (const __attribute__((address_space(1))) void*)g,
      (__attribute__((address_space(3))) void*)s, 16, 0, 0);
}

// ---------------- set-norm statistics (two-stage, deterministic) -----------
// slice s: s<4 -> p0 batch s ; s>=4 -> p1 batch s-4. 524288 elems per slice.
__global__ __launch_bounds__(256) void stats_partial(const float* __restrict__ p0,
                                                     const float* __restrict__ p1,
                                                     float2* __restrict__ partial) {
  const int s = blockIdx.y;
  const float* p = (s >= 4 ? p1 + (size_t)(s - 4) * 524288 : p0 + (size_t)s * 524288)
                   + (size_t)blockIdx.x * 8192;
  float sum = 0.f, ss = 0.f;
#pragma unroll
  for (int j = 0; j < 8; ++j) {
    f32x4 v = *reinterpret_cast<const f32x4*>(p + (size_t)(j * 256 + threadIdx.x) * 4);
#pragma unroll
    for (int e = 0; e < 4; ++e) { sum += v[e]; ss += v[e] * v[e]; }
  }
#pragma unroll
  for (int m = 1; m < 64; m <<= 1) { sum += __shfl_xor(sum, m); ss += __shfl_xor(ss, m); }
  __shared__ float2 red[4];
  if ((threadIdx.x & 63) == 0) red[threadIdx.x >> 6] = make_float2(sum, ss);
  __syncthreads();
  if (threadIdx.x == 0) {
    float a = 0.f, b = 0.f;
    for (int i = 0; i < 4; ++i) { a += red[i].x; b += red[i].y; }
    partial[s * 64 + blockIdx.x] = make_float2(a, b);
  }
}

__global__ void stats_final(const float2* __restrict__ partial, float2* __restrict__ stats) {
  const int s = blockIdx.x;
  float2 v = partial[s * 64 + threadIdx.x];
  float sum = v.x, ss = v.y;
#pragma unroll
  for (int m = 1; m < 64; m <<= 1) { sum += __shfl_xor(sum, m); ss += __shfl_xor(ss, m); }
  if (threadIdx.x == 0) {
    const float invN = 1.f / 524288.f;
    float mean = sum * invN;
    float var = fmaxf(ss * invN - mean * mean, 0.f);
    stats[s] = make_float2(mean, rsqrtf(var + 1e-5f));
  }
}

// ---------------- f32 -> f16 prep (optional fused setnorm / relu) ----------
// 4*2048*256 = 2097152 elements, 8 per thread -> grid 1024 x 256.
template <bool NORM, bool RELU>
__global__ __launch_bounds__(256) void prep_cast(const float* __restrict__ in, f16* __restrict__ out,
                                                 const float2* __restrict__ stats, int sbase,
                                                 const float* __restrict__ w, const float* __restrict__ b) {
  const size_t i8 = (size_t)blockIdx.x * 256 + threadIdx.x;
  const size_t idx = i8 * 8;
  float mean = 0.f, istd = 1.f;
  if (NORM) { float2 st = stats[sbase + (int)(idx >> 19)]; mean = st.x; istd = st.y; }
  const int f = (int)(idx & 255);
  f32x4 v0 = *reinterpret_cast<const f32x4*>(in + idx);
  f32x4 v1 = *reinterpret_cast<const f32x4*>(in + idx + 4);
  f32x4 w0, w1, b0, b1;
  if (NORM) {
    w0 = *reinterpret_cast<const f32x4*>(w + f);
    w1 = *reinterpret_cast<const f32x4*>(w + f + 4);
    b0 = *reinterpret_cast<const f32x4*>(b + f);
    b1 = *reinterpret_cast<const f32x4*>(b + f + 4);
  }
  f16x8 o;
#pragma unroll
  for (int j = 0; j < 4; ++j) {
    float x0 = v0[j], x1 = v1[j];
    if (NORM) { x0 = (x0 - mean) * istd * w0[j] + b0[j]; x1 = (x1 - mean) * istd * w1[j] + b1[j]; }
    if (RELU) { x0 = fmaxf(x0, 0.f); x1 = fmaxf(x1, 0.f); }
    o[j] = (f16)x0;
    o[j + 4] = (f16)x1;
  }
  *reinterpret_cast<f16x8*>(out + idx) = o;
}

// weights: 5 x [256x256] f32 -> concat f16. grid 160 x 256.
__global__ __launch_bounds__(256) void cast_w(const float* __restrict__ w0, const float* __restrict__ w1,
                                              const float* __restrict__ w2, const float* __restrict__ w3,
                                              const float* __restrict__ w4, f16* __restrict__ out) {
  const int i8 = blockIdx.x * 256 + threadIdx.x;  // 0..40959
  const int mat = i8 >> 13;
  const size_t off = (size_t)(i8 & 8191) * 8;
  const float* src = mat == 0 ? w0 : mat == 1 ? w1 : mat == 2 ? w2 : mat == 3 ? w3 : w4;
  f32x4 v0 = *reinterpret_cast<const f32x4*>(src + off);
  f32x4 v1 = *reinterpret_cast<const f32x4*>(src + off + 4);
  f16x8 o;
#pragma unroll
  for (int j = 0; j < 4; ++j) { o[j] = (f16)v0[j]; o[j + 4] = (f16)v1[j]; }
  *reinterpret_cast<f16x8*>(out + (size_t)mat * 65536 + off) = o;
}

// ---------------- GEMM: C[8192][256] = A[8192][256] . W[256][256]^T --------
// 64x64 tile, 4 waves (2x2), BK=32, K=256. out = (acc + bias) * scale [+resid]
enum { GM_F16 = 0, GM_VT = 1, GM_F32R = 2 };

template <int MODE>
__global__ __launch_bounds__(256) void gemm_nt(const f16* __restrict__ A, const f16* __restrict__ W,
                                               const float* __restrict__ bias,
                                               const float* __restrict__ resid,
                                               void* __restrict__ outp, float scale) {
  __shared__ __align__(16) f16 lds[4096];  // A: [kg4][row64][8], B: same, 4KB each
  const int t = threadIdx.x;
  const int w = t >> 6, lane = t & 63;
  const int g = lane >> 4, lq = lane & 15;
  const int m0 = blockIdx.x * 64, n0 = blockIdx.y * 64;
  const int wr = (w >> 1) * 32, wc = (w & 1) * 32;

  f32x4 acc[2][2] = {};
  f16* ldsA = lds;
  f16* ldsB = lds + 2048;
  const f16* gA = A + (size_t)(m0 + lane) * 256 + w * 8;  // chunk = t: kg=w,row=lane
  const f16* gB = W + (size_t)(n0 + lane) * 256 + w * 8;
  f16* dA = ldsA + t * 8;
  f16* dB = ldsB + t * 8;

  for (int kt = 0; kt < 8; ++kt) {
    __syncthreads();
    load_lds16(gA + kt * 32, dA);
    load_lds16(gB + kt * 32, dB);
    __syncthreads();
    f16x8 af[2], bfr[2];
#pragma unroll
    for (int i = 0; i < 2; ++i)
      af[i] = *reinterpret_cast<const f16x8*>(ldsA + g * 512 + (wr + i * 16 + lq) * 8);
#pragma unroll
    for (int j = 0; j < 2; ++j)
      bfr[j] = *reinterpret_cast<const f16x8*>(ldsB + g * 512 + (wc + j * 16 + lq) * 8);
#pragma unroll
    for (int i = 0; i < 2; ++i)
#pragma unroll
      for (int j = 0; j < 2; ++j)
        acc[i][j] = __builtin_amdgcn_mfma_f32_16x16x32_f16(af[i], bfr[j], acc[i][j], 0, 0, 0);
  }

#pragma unroll
  for (int i = 0; i < 2; ++i)
#pragma unroll
    for (int j = 0; j < 2; ++j) {
      const int row0 = m0 + wr + i * 16 + g * 4;
      const int col = n0 + wc + j * 16 + lq;
      const float bv = bias[col];
#pragma unroll
      for (int r = 0; r < 4; ++r) {
        const int rr = row0 + r;
        float v = (acc[i][j][r] + bv) * scale;
        if constexpr (MODE == GM_F16) {
          ((f16*)outp)[(size_t)rr * 256 + col] = (f16)v;
        } else if constexpr (MODE == GM_VT) {
          // transposed per-batch: Vt[b][feat][row] for contiguous PV B-frags
          ((f16*)outp)[((size_t)(rr >> 11) * 256 + col) * 2048 + (rr & 2047)] = (f16)v;
        } else {
          const size_t o = (size_t)rr * 256 + col;
          ((float*)outp)[o] = v + resid[o];
        }
      }
    }
}

// ---------------- flash attention --------------------------------------------
// grid (32 qtiles, 8 heads, 4 batch), 256 thr = 4 waves, wave = 16 q-rows.
// Q pre-scaled by 1/16. K: [B*2048][256]. Vt: [B][256][2048]. O: [B*2048][256].
__global__ __launch_bounds__(256) void attn_kernel(const f16* __restrict__ Q,
                                                   const f16* __restrict__ K,
                                                   const f16* __restrict__ Vt,
                                                   f16* __restrict__ O) {
  __shared__ __align__(16) f16 plds[4][1024];  // per-wave private P tile [16][64], XOR-swizzled
  const int t = threadIdx.x;
  const int w = t >> 6, lane = t & 63;
  const int g = lane >> 4, lq = lane & 15;
  const int qt = blockIdx.x, h = blockIdx.y, b = blockIdx.z;
  const int q0 = qt * 64 + w * 16;

  const f16* Kb = K + (size_t)b * 2048 * 256 + h * 32;
  const f16* Vb = Vt + ((size_t)b * 256 + h * 32) * 2048;
  f16* myp = plds[w];

  const f16x8 qf =
      *reinterpret_cast<const f16x8*>(Q + (size_t)(b * 2048 + q0 + lq) * 256 + h * 32 + g * 8);

  f32x4 o0 = {0.f, 0.f, 0.f, 0.f}, o1 = {0.f, 0.f, 0.f, 0.f};
  float m_[4] = {-1e30f, -1e30f, -1e30f, -1e30f};
  float l_[4] = {0.f, 0.f, 0.f, 0.f};

  for (int kt = 0; kt < 32; ++kt) {
    const f16* Kt = Kb + (size_t)kt * 64 * 256;
    f32x4 s[4];
#pragma unroll
    for (int c = 0; c < 4; ++c) {
      f16x8 kf = *reinterpret_cast<const f16x8*>(Kt + (size_t)(c * 16 + lq) * 256 + g * 8);
      f32x4 z = {0.f, 0.f, 0.f, 0.f};
      s[c] = __builtin_amdgcn_mfma_f32_16x16x32_f16(qf, kf, z, 0, 0, 0);
    }
    float sc[4];
#pragma unroll
    for (int r = 0; r < 4; ++r) {
      float x = fmaxf(fmaxf(s[0][r], s[1][r]), fmaxf(s[2][r], s[3][r]));
      x = fmaxf(x, __shfl_xor(x, 1));
      x = fmaxf(x, __shfl_xor(x, 2));
      x = fmaxf(x, __shfl_xor(x, 4));
      x = fmaxf(x, __shfl_xor(x, 8));
      const float mnew = fmaxf(m_[r], x);
      sc[r] = __expf(m_[r] - mnew);
      m_[r] = mnew;
      float sum = 0.f;
#pragma unroll
      for (int c = 0; c < 4; ++c) {
        float p = __expf(s[c][r] - mnew);
        s[c][r] = p;
        sum += p;
      }
      sum += __shfl_xor(sum, 1);
      sum += __shfl_xor(sum, 2);
      sum += __shfl_xor(sum, 4);
      sum += __shfl_xor(sum, 8);
      l_[r] = l_[r] * sc[r] + sum;
    }
    // P -> LDS (swizzle flips elem bits 3..5 with q&7 so PV b128 reads are balanced)
#pragma unroll
    for (int c = 0; c < 4; ++c)
#pragma unroll
      for (int r = 0; r < 4; ++r) {
        const int q = g * 4 + r, k = c * 16 + lq;
        myp[(q * 64 + k) ^ ((q & 7) << 3)] = (f16)s[c][r];
      }
#pragma unroll
    for (int r = 0; r < 4; ++r) { o0[r] *= sc[r]; o1[r] *= sc[r]; }
#pragma unroll
    for (int ch = 0; ch < 2; ++ch) {
      f16x8 pa = *reinterpret_cast<const f16x8*>(myp + ((lq * 64 + ch * 32 + g * 8) ^ ((lq & 7) << 3)));
      f16x8 v0 = *reinterpret_cast<const f16x8*>(Vb + (size_t)lq * 2048 + kt * 64 + ch * 32 + g * 8);
      f16x8 v1 = *reinterpret_cast<const f16x8*>(Vb + (size_t)(16 + lq) * 2048 + kt * 64 + ch * 32 + g * 8);
      o0 = __builtin_amdgcn_mfma_f32_16x16x32_f16(pa, v0, o0, 0, 0, 0);
      o1 = __builtin_amdgcn_mfma_f32_16x16x32_f16(pa, v1, o1, 0, 0, 0);
    }
  }
#pragma unroll
  for (int r = 0; r < 4; ++r) {
    const float inv = 1.f / l_[r];
    const size_t row = (size_t)b * 2048 + q0 + g * 4 + r;
    O[row * 256 + h * 32 + lq] = (f16)(o0[r] * inv);
    O[row * 256 + h * 32 + 16 + lq] = (f16)(o1[r] * inv);
  }
}

// ---------------------------------------------------------------------------
extern "C" void kernel_launch(void* const* d_in, const int* in_sizes, int n_in,
                              void* d_out, int out_size, void* d_ws, size_t ws_size,
                              hipStream_t stream) {
  (void)in_sizes; (void)n_in; (void)out_size; (void)ws_size;
  const float* X    = (const float*)d_in[0];
  const float* Y    = (const float*)d_in[1];
  const float* Wq   = (const float*)d_in[2];
  const float* bq   = (const float*)d_in[3];
  const float* Wk   = (const float*)d_in[4];
  const float* bk   = (const float*)d_in[5];
  const float* Wv   = (const float*)d_in[6];
  const float* bv   = (const float*)d_in[7];
  const float* Wo   = (const float*)d_in[8];
  const float* bo   = (const float*)d_in[9];
  const float* Wres = (const float*)d_in[10];
  const float* bres = (const float*)d_in[11];
  const float* nq_w = (const float*)d_in[12];
  const float* nq_b = (const float*)d_in[13];
  const float* nk_w = (const float*)d_in[14];
  const float* nk_b = (const float*)d_in[15];
  const float* n0_w = (const float*)d_in[16];
  const float* n0_b = (const float*)d_in[17];
  float* out = (float*)d_out;

  // workspace layout (compact, ~21.1 MB total):
  // five 4 MiB f16 [4*2048*256] buffers + 640 KiB weights + stats
  char* ws = (char*)d_ws;
  const size_t MB = 1u << 20;
  f16* bufA = (f16*)(ws + 0 * MB);    // Xn   -> later Vt
  f16* bufB = (f16*)(ws + 4 * MB);    // Yn   -> later attn out
  f16* bufC = (f16*)(ws + 8 * MB);    // Ycast-> later relu(setnorm(H1))
  f16* bufQ = (f16*)(ws + 12 * MB);
  f16* bufK = (f16*)(ws + 16 * MB);
  f16* bufW = (f16*)(ws + 20 * MB);   // 5 x 65536 f16 = 640 KiB
  float2* partial = (float2*)(ws + 21 * MB);          // 8*64 float2 = 4 KiB
  float2* stats   = (float2*)(ws + 21 * MB + 4096);   // 8 float2

  // 1. set-norm stats for X (slices 0-3) and Y (slices 4-7)
  stats_partial<<<dim3(64, 8), 256, 0, stream>>>(X, Y, partial);
  stats_final<<<8, 64, 0, stream>>>(partial, stats);

  // 2. f16 preps (2097152 elems / 8 per thread = 1024 blocks)
  prep_cast<true, false><<<1024, 256, 0, stream>>>(X, bufA, stats, 0, nq_w, nq_b);
  prep_cast<true, false><<<1024, 256, 0, stream>>>(Y, bufB, stats, 4, nk_w, nk_b);
  prep_cast<false, false><<<1024, 256, 0, stream>>>(Y, bufC, stats, 0, nq_w, nq_b);
  cast_w<<<160, 256, 0, stream>>>(Wq, Wk, Wv, Wo, Wres, bufW);

  // 3. projections (Q pre-scaled by 1/sqrt(256); V stored transposed per batch)
  gemm_nt<GM_F16><<<dim3(128, 4), 256, 0, stream>>>(bufA, bufW + 0 * 65536, bq, nullptr, bufQ, 1.f / 16.f);
  gemm_nt<GM_F16><<<dim3(128, 4), 256, 0, stream>>>(bufB, bufW + 1 * 65536, bk, nullptr, bufK, 1.f);
  gemm_nt<GM_VT ><<<dim3(128, 4), 256, 0, stream>>>(bufC, bufW + 2 * 65536, bv, nullptr, bufA, 1.f);

  // 4. attention (out -> bufB)
  attn_kernel<<<dim3(32, 8, 4), 256, 0, stream>>>(bufQ, bufK, bufA, bufB);

  // 5. O projection + X residual -> H1 (in d_out, f32)
  gemm_nt<GM_F32R><<<dim3(128, 4), 256, 0, stream>>>(bufB, bufW + 3 * 65536, bo, X, out, 1.f);

  // 6. stats over H1, relu(setnorm(H1)) -> bufC
  stats_partial<<<dim3(64, 4), 256, 0, stream>>>(out, out, partial);
  stats_final<<<4, 64, 0, stream>>>(partial, stats);
  prep_cast<true, true><<<1024, 256, 0, stream>>>(out, bufC, stats, 0, n0_w, n0_b);

  // 7. final: out = H1 + relu(setnorm(H1)) @ Wres^T + bres (in-place per element)
  gemm_nt<GM_F32R><<<dim3(128, 4), 256, 0, stream>>>(bufC, bufW + 4 * 65536, bres, out, out, 1.f);
}

// Round 3
// 193.063 us; speedup vs baseline: 1.0132x; 1.0132x over previous
//
#include <hip/hip_runtime.h>

// ---------------------------------------------------------------------------
// MABClean: setnorm -> {Q,K,V} proj -> 8-head attention -> O proj + residual
//           -> setnorm -> relu -> Wres proj + residual.
// B=4, Nx=Ny=2048, d_model=256, heads=8, head_dim=32. All f32 in/out.
// Compute in f16 MFMA (f32 accum), stats/softmax/residuals in f32.
// Attention: swapped QK^T (lane-local P rows), exp2 domain, defer-max rescale.
// ---------------------------------------------------------------------------

typedef _Float16 f16;
typedef _Float16 f16x4 __attribute__((ext_vector_type(4)));
typedef _Float16 f16x8 __attribute__((ext_vector_type(8)));
typedef float f32x4 __attribute__((ext_vector_type(4)));

#define DEV static __device__ __forceinline__

DEV void load_lds16(const void* g, void* s) {
  __builtin_amdgcn_global_load_lds(
      (const __attribute__((address_space(1))) void*)g,
      (__attribute__((address_space(3))) void*)s, 16, 0, 0);
}

// ---------------- set-norm statistics (two-stage, deterministic) -----------
// slice s: s<4 -> p0 batch s ; s>=4 -> p1 batch s-4. 524288 elems per slice.
__global__ __launch_bounds__(256) void stats_partial(const float* __restrict__ p0,
                                                     const float* __restrict__ p1,
                                                     float2* __restrict__ partial) {
  const int s = blockIdx.y;
  const float* p = (s >= 4 ? p1 + (size_t)(s - 4) * 524288 : p0 + (size_t)s * 524288)
                   + (size_t)blockIdx.x * 8192;
  float sum = 0.f, ss = 0.f;
#pragma unroll
  for (int j = 0; j < 8; ++j) {
    f32x4 v = *reinterpret_cast<const f32x4*>(p + (size_t)(j * 256 + threadIdx.x) * 4);
#pragma unroll
    for (int e = 0; e < 4; ++e) { sum += v[e]; ss += v[e] * v[e]; }
  }
#pragma unroll
  for (int m = 1; m < 64; m <<= 1) { sum += __shfl_xor(sum, m); ss += __shfl_xor(ss, m); }
  __shared__ float2 red[4];
  if ((threadIdx.x & 63) == 0) red[threadIdx.x >> 6] = make_float2(sum, ss);
  __syncthreads();
  if (threadIdx.x == 0) {
    float a = 0.f, b = 0.f;
    for (int i = 0; i < 4; ++i) { a += red[i].x; b += red[i].y; }
    partial[s * 64 + blockIdx.x] = make_float2(a, b);
  }
}

__global__ void stats_final(const float2* __restrict__ partial, float2* __restrict__ stats) {
  const int s = blockIdx.x;
  float2 v = partial[s * 64 + threadIdx.x];
  float sum = v.x, ss = v.y;
#pragma unroll
  for (int m = 1; m < 64; m <<= 1) { sum += __shfl_xor(sum, m); ss += __shfl_xor(ss, m); }
  if (threadIdx.x == 0) {
    const float invN = 1.f / 524288.f;
    float mean = sum * invN;
    float var = fmaxf(ss * invN - mean * mean, 0.f);
    stats[s] = make_float2(mean, rsqrtf(var + 1e-5f));
  }
}

// ---------------- f32 -> f16 prep (optional fused setnorm / relu) ----------
// 4*2048*256 = 2097152 elements, 8 per thread -> grid 1024 x 256.
template <bool NORM, bool RELU>
__global__ __launch_bounds__(256) void prep_cast(const float* __restrict__ in, f16* __restrict__ out,
                                                 const float2* __restrict__ stats, int sbase,
                                                 const float* __restrict__ w, const float* __restrict__ b) {
  const size_t i8 = (size_t)blockIdx.x * 256 + threadIdx.x;
  const size_t idx = i8 * 8;
  float mean = 0.f, istd = 1.f;
  if (NORM) { float2 st = stats[sbase + (int)(idx >> 19)]; mean = st.x; istd = st.y; }
  const int f = (int)(idx & 255);
  f32x4 v0 = *reinterpret_cast<const f32x4*>(in + idx);
  f32x4 v1 = *reinterpret_cast<const f32x4*>(in + idx + 4);
  f32x4 w0, w1, b0, b1;
  if (NORM) {
    w0 = *reinterpret_cast<const f32x4*>(w + f);
    w1 = *reinterpret_cast<const f32x4*>(w + f + 4);
    b0 = *reinterpret_cast<const f32x4*>(b + f);
    b1 = *reinterpret_cast<const f32x4*>(b + f + 4);
  }
  f16x8 o;
#pragma unroll
  for (int j = 0; j < 4; ++j) {
    float x0 = v0[j], x1 = v1[j];
    if (NORM) { x0 = (x0 - mean) * istd * w0[j] + b0[j]; x1 = (x1 - mean) * istd * w1[j] + b1[j]; }
    if (RELU) { x0 = fmaxf(x0, 0.f); x1 = fmaxf(x1, 0.f); }
    o[j] = (f16)x0;
    o[j + 4] = (f16)x1;
  }
  *reinterpret_cast<f16x8*>(out + idx) = o;
}

// weights: 5 x [256x256] f32 -> concat f16. grid 160 x 256.
__global__ __launch_bounds__(256) void cast_w(const float* __restrict__ w0, const float* __restrict__ w1,
                                              const float* __restrict__ w2, const float* __restrict__ w3,
                                              const float* __restrict__ w4, f16* __restrict__ out) {
  const int i8 = blockIdx.x * 256 + threadIdx.x;  // 0..40959
  const int mat = i8 >> 13;
  const size_t off = (size_t)(i8 & 8191) * 8;
  const float* src = mat == 0 ? w0 : mat == 1 ? w1 : mat == 2 ? w2 : mat == 3 ? w3 : w4;
  f32x4 v0 = *reinterpret_cast<const f32x4*>(src + off);
  f32x4 v1 = *reinterpret_cast<const f32x4*>(src + off + 4);
  f16x8 o;
#pragma unroll
  for (int j = 0; j < 4; ++j) { o[j] = (f16)v0[j]; o[j + 4] = (f16)v1[j]; }
  *reinterpret_cast<f16x8*>(out + (size_t)mat * 65536 + off) = o;
}

// ---------------- GEMM: C[8192][256] = A[8192][256] . W[256][256]^T --------
// 64x64 tile, 4 waves (2x2), BK=32, K=256. out = (acc + bias) * scale [+resid]
enum { GM_F16 = 0, GM_VT = 1, GM_F32R = 2 };

template <int MODE>
__global__ __launch_bounds__(256) void gemm_nt(const f16* __restrict__ A, const f16* __restrict__ W,
                                               const float* __restrict__ bias,
                                               const float* __restrict__ resid,
                                               void* __restrict__ outp, float scale) {
  __shared__ __align__(16) f16 lds[4096];  // A: [kg4][row64][8], B: same, 4KB each
  const int t = threadIdx.x;
  const int w = t >> 6, lane = t & 63;
  const int g = lane >> 4, lq = lane & 15;
  const int m0 = blockIdx.x * 64, n0 = blockIdx.y * 64;
  const int wr = (w >> 1) * 32, wc = (w & 1) * 32;

  f32x4 acc[2][2] = {};
  f16* ldsA = lds;
  f16* ldsB = lds + 2048;
  const f16* gA = A + (size_t)(m0 + lane) * 256 + w * 8;  // chunk = t: kg=w,row=lane
  const f16* gB = W + (size_t)(n0 + lane) * 256 + w * 8;
  f16* dA = ldsA + t * 8;
  f16* dB = ldsB + t * 8;

  for (int kt = 0; kt < 8; ++kt) {
    __syncthreads();
    load_lds16(gA + kt * 32, dA);
    load_lds16(gB + kt * 32, dB);
    __syncthreads();
    f16x8 af[2], bfr[2];
#pragma unroll
    for (int i = 0; i < 2; ++i)
      af[i] = *reinterpret_cast<const f16x8*>(ldsA + g * 512 + (wr + i * 16 + lq) * 8);
#pragma unroll
    for (int j = 0; j < 2; ++j)
      bfr[j] = *reinterpret_cast<const f16x8*>(ldsB + g * 512 + (wc + j * 16 + lq) * 8);
#pragma unroll
    for (int i = 0; i < 2; ++i)
#pragma unroll
      for (int j = 0; j < 2; ++j)
        acc[i][j] = __builtin_amdgcn_mfma_f32_16x16x32_f16(af[i], bfr[j], acc[i][j], 0, 0, 0);
  }

#pragma unroll
  for (int i = 0; i < 2; ++i)
#pragma unroll
    for (int j = 0; j < 2; ++j) {
      const int row0 = m0 + wr + i * 16 + g * 4;
      const int col = n0 + wc + j * 16 + lq;
      const float bv = bias[col];
#pragma unroll
      for (int r = 0; r < 4; ++r) {
        const int rr = row0 + r;
        float v = (acc[i][j][r] + bv) * scale;
        if constexpr (MODE == GM_F16) {
          ((f16*)outp)[(size_t)rr * 256 + col] = (f16)v;
        } else if constexpr (MODE == GM_VT) {
          // transposed per-batch: Vt[b][feat][row] for contiguous PV B-frags
          ((f16*)outp)[((size_t)(rr >> 11) * 256 + col) * 2048 + (rr & 2047)] = (f16)v;
        } else {
          const size_t o = (size_t)rr * 256 + col;
          ((float*)outp)[o] = v + resid[o];
        }
      }
    }
}

// ---------------- flash attention --------------------------------------------
// grid (32 qtiles, 8 heads, 4 batch), 256 thr = 4 waves, wave = 16 q-rows.
// Q pre-scaled by log2(e)/16 (exp2 domain). K: [B*2048][256]. Vt: [B][256][2048].
// Swapped QK^T: s[c] = mfma(kf, qf) -> lane holds 16 S-values of q-row (lane&15)
// at k = c*16 + g*4 + r. Softmax reductions are in-register (+2 shuffles for max).
__global__ __launch_bounds__(256) void attn_kernel(const f16* __restrict__ Q,
                                                   const f16* __restrict__ K,
                                                   const f16* __restrict__ Vt,
                                                   f16* __restrict__ O) {
  __shared__ __align__(16) f16 plds[4][1024];  // per-wave P tile [16 q][64 k], XOR-swizzled
  const int t = threadIdx.x;
  const int w = t >> 6, lane = t & 63;
  const int g = lane >> 4, lq = lane & 15;
  const int qt = blockIdx.x, h = blockIdx.y, b = blockIdx.z;
  const int q0 = qt * 64 + w * 16;
  const float THR = 8.0f;  // defer-max threshold (exp2 domain): P bounded by 2^8

  const f16* Kb = K + (size_t)b * 2048 * 256 + h * 32;
  const f16* Vb = Vt + ((size_t)b * 256 + h * 32) * 2048;
  f16* myp = plds[w];

  const f16x8 qf =
      *reinterpret_cast<const f16x8*>(Q + (size_t)(b * 2048 + q0 + lq) * 256 + h * 32 + g * 8);

  // swizzled LDS addresses (elem idx), bits 3..5 XORed with q&7
  const int wbase0 = (lq * 64 + g * 4);
  const int xq = (lq & 7) << 3;

  f32x4 o0 = {0.f, 0.f, 0.f, 0.f}, o1 = {0.f, 0.f, 0.f, 0.f};
  float m_ = -1e30f;  // running row max (exp2 domain), shared across g-lanes of a q-row
  float l_ = 0.f;     // per-lane PARTIAL row sum (own 16 k-slots); combined at end

  for (int kt = 0; kt < 32; ++kt) {
    const f16* Kt = Kb + (size_t)kt * 64 * 256;
    f32x4 s[4];
#pragma unroll
    for (int c = 0; c < 4; ++c) {
      f16x8 kf = *reinterpret_cast<const f16x8*>(Kt + (size_t)(c * 16 + lq) * 256 + g * 8);
      f32x4 z = {0.f, 0.f, 0.f, 0.f};
      s[c] = __builtin_amdgcn_mfma_f32_16x16x32_f16(kf, qf, z, 0, 0, 0);  // S^T: lane q=lq
    }
    // row max over this tile: 15 in-register + 2 shuffles (across g)
    float x0 = fmaxf(fmaxf(s[0][0], s[0][1]), fmaxf(s[0][2], s[0][3]));
    float x1 = fmaxf(fmaxf(s[1][0], s[1][1]), fmaxf(s[1][2], s[1][3]));
    float x2 = fmaxf(fmaxf(s[2][0], s[2][1]), fmaxf(s[2][2], s[2][3]));
    float x3 = fmaxf(fmaxf(s[3][0], s[3][1]), fmaxf(s[3][2], s[3][3]));
    float x = fmaxf(fmaxf(x0, x1), fmaxf(x2, x3));
    x = fmaxf(x, __shfl_xor(x, 16));
    x = fmaxf(x, __shfl_xor(x, 32));

    if (__any(x > m_ + THR)) {  // rescale path (rare after first tile)
      const float mnew = fmaxf(m_, x);
      const float sc = __builtin_exp2f(m_ - mnew);
      m_ = mnew;
      l_ *= sc;
      // O rows live at q = g*4+r; sc lives at q = lq -> redistribute via 4 shuffles
#pragma unroll
      for (int r = 0; r < 4; ++r) {
        const float scq = __shfl(sc, g * 4 + r);
        o0[r] *= scq;
        o1[r] *= scq;
      }
    }

    // p = exp2(s - m), accumulate partial row sum in-register
    float lad = 0.f;
#pragma unroll
    for (int c = 0; c < 4; ++c)
#pragma unroll
      for (int r = 0; r < 4; ++r) {
        const float p = __builtin_exp2f(s[c][r] - m_);
        s[c][r] = p;
        lad += p;
      }
    l_ += lad;

    // pack P rows to LDS: 4 x ds_write_b64 (k consecutive in r)
#pragma unroll
    for (int c = 0; c < 4; ++c) {
      f16x4 pk;
#pragma unroll
      for (int r = 0; r < 4; ++r) pk[r] = (f16)s[c][r];
      *reinterpret_cast<f16x4*>(myp + ((wbase0 + c * 16) ^ xq)) = pk;
    }

#pragma unroll
    for (int ch = 0; ch < 2; ++ch) {
      f16x8 pa = *reinterpret_cast<const f16x8*>(myp + ((lq * 64 + ch * 32 + g * 8) ^ xq));
      f16x8 v0 = *reinterpret_cast<const f16x8*>(Vb + (size_t)lq * 2048 + kt * 64 + ch * 32 + g * 8);
      f16x8 v1 = *reinterpret_cast<const f16x8*>(Vb + (size_t)(16 + lq) * 2048 + kt * 64 + ch * 32 + g * 8);
      o0 = __builtin_amdgcn_mfma_f32_16x16x32_f16(pa, v0, o0, 0, 0, 0);
      o1 = __builtin_amdgcn_mfma_f32_16x16x32_f16(pa, v1, o1, 0, 0, 0);
    }
  }

  // combine partial sums across the 4 g-lanes of each q-row
  float lf = l_ + __shfl_xor(l_, 16);
  lf += __shfl_xor(lf, 32);
#pragma unroll
  for (int r = 0; r < 4; ++r) {
    const float lr = __shfl(lf, g * 4 + r);  // l for q = g*4+r
    const float inv = 1.f / lr;
    const size_t row = (size_t)b * 2048 + q0 + g * 4 + r;
    O[row * 256 + h * 32 + lq] = (f16)(o0[r] * inv);
    O[row * 256 + h * 32 + 16 + lq] = (f16)(o1[r] * inv);
  }
}

// ---------------------------------------------------------------------------
extern "C" void kernel_launch(void* const* d_in, const int* in_sizes, int n_in,
                              void* d_out, int out_size, void* d_ws, size_t ws_size,
                              hipStream_t stream) {
  (void)in_sizes; (void)n_in; (void)out_size; (void)ws_size;
  const float* X    = (const float*)d_in[0];
  const float* Y    = (const float*)d_in[1];
  const float* Wq   = (const float*)d_in[2];
  const float* bq   = (const float*)d_in[3];
  const float* Wk   = (const float*)d_in[4];
  const float* bk   = (const float*)d_in[5];
  const float* Wv   = (const float*)d_in[6];
  const float* bv   = (const float*)d_in[7];
  const float* Wo   = (const float*)d_in[8];
  const float* bo   = (const float*)d_in[9];
  const float* Wres = (const float*)d_in[10];
  const float* bres = (const float*)d_in[11];
  const float* nq_w = (const float*)d_in[12];
  const float* nq_b = (const float*)d_in[13];
  const float* nk_w = (const float*)d_in[14];
  const float* nk_b = (const float*)d_in[15];
  const float* n0_w = (const float*)d_in[16];
  const float* n0_b = (const float*)d_in[17];
  float* out = (float*)d_out;

  // workspace layout (compact, ~21.1 MB total)
  char* ws = (char*)d_ws;
  const size_t MB = 1u << 20;
  f16* bufA = (f16*)(ws + 0 * MB);    // Xn   -> later Vt
  f16* bufB = (f16*)(ws + 4 * MB);    // Yn   -> later attn out
  f16* bufC = (f16*)(ws + 8 * MB);    // Ycast-> later relu(setnorm(H1))
  f16* bufQ = (f16*)(ws + 12 * MB);
  f16* bufK = (f16*)(ws + 16 * MB);
  f16* bufW = (f16*)(ws + 20 * MB);   // 5 x 65536 f16 = 640 KiB
  float2* partial = (float2*)(ws + 21 * MB);          // 8*64 float2 = 4 KiB
  float2* stats   = (float2*)(ws + 21 * MB + 4096);   // 8 float2

  // 1. set-norm stats for X (slices 0-3) and Y (slices 4-7)
  stats_partial<<<dim3(64, 8), 256, 0, stream>>>(X, Y, partial);
  stats_final<<<8, 64, 0, stream>>>(partial, stats);

  // 2. f16 preps (2097152 elems / 8 per thread = 1024 blocks)
  prep_cast<true, false><<<1024, 256, 0, stream>>>(X, bufA, stats, 0, nq_w, nq_b);
  prep_cast<true, false><<<1024, 256, 0, stream>>>(Y, bufB, stats, 4, nk_w, nk_b);
  prep_cast<false, false><<<1024, 256, 0, stream>>>(Y, bufC, stats, 0, nq_w, nq_b);
  cast_w<<<160, 256, 0, stream>>>(Wq, Wk, Wv, Wo, Wres, bufW);

  // 3. projections. Q pre-scaled by log2(e)/sqrt(256) so softmax runs in exp2
  //    domain; V stored transposed per batch.
  const float qscale = 1.4426950408889634f / 16.f;
  gemm_nt<GM_F16><<<dim3(128, 4), 256, 0, stream>>>(bufA, bufW + 0 * 65536, bq, nullptr, bufQ, qscale);
  gemm_nt<GM_F16><<<dim3(128, 4), 256, 0, stream>>>(bufB, bufW + 1 * 65536, bk, nullptr, bufK, 1.f);
  gemm_nt<GM_VT ><<<dim3(128, 4), 256, 0, stream>>>(bufC, bufW + 2 * 65536, bv, nullptr, bufA, 1.f);

  // 4. attention (out -> bufB)
  attn_kernel<<<dim3(32, 8, 4), 256, 0, stream>>>(bufQ, bufK, bufA, bufB);

  // 5. O projection + X residual -> H1 (in d_out, f32)
  gemm_nt<GM_F32R><<<dim3(128, 4), 256, 0, stream>>>(bufB, bufW + 3 * 65536, bo, X, out, 1.f);

  // 6. stats over H1, relu(setnorm(H1)) -> bufC
  stats_partial<<<dim3(64, 4), 256, 0, stream>>>(out, out, partial);
  stats_final<<<4, 64, 0, stream>>>(partial, stats);
  prep_cast<true, true><<<1024, 256, 0, stream>>>(out, bufC, stats, 0, n0_w, n0_b);

  // 7. final: out = H1 + relu(setnorm(H1)) @ Wres^T + bres (in-place per element)
  gemm_nt<GM_F32R><<<dim3(128, 4), 256, 0, stream>>>(bufC, bufW + 4 * 65536, bres, out, out, 1.f);
}